// Round 10
// baseline (126.146 us; speedup 1.0000x reference)
//
#include <hip/hip_runtime.h>
#include <math.h>

#define NTOK 16384
#define DDIM 2048
#define NEXP 64
#define MT   128                 // tokens per stage-1 block (32 groups x 4)
#define KSPLIT 8
#define KRANGE (DDIM / KSPLIT)   // 256

// ws layout (floats): [0..63] f counts, [64..127] P sums, [128] sum lse^2,
// [256 ...] partial logits: [KSPLIT][NTOK][NEXP]
#define PART_OFF 256

__global__ void zero_acc(float* acc) {
    int t = threadIdx.x;
    if (t < 129) acc[t] = 0.0f;
}

// No-LDS GEMM: x rows register-streamed (read once device-wide, L3-resident),
// W rows from L2 (8-lane dedup per wave). No barriers -> compiler pipelines
// loads with counted vmcnt freely.
__global__ __launch_bounds__(256, 4) void gemm_part(
    const float* __restrict__ x, const float* __restrict__ W,
    float* __restrict__ pws)
{
    const int tid  = threadIdx.x;
    const int tb   = blockIdx.x & (NTOK / MT - 1);  // token block 0..127
    const int s    = blockIdx.x >> 7;               // k-split 0..7
    const int tok0 = tb * MT;
    const int kb   = s * KRANGE;

    const int tx = tid & 7;              // experts 8tx..8tx+7
    const int ty = tid >> 3;             // tokens 4ty..4ty+3 (0..31)
    const int e0 = tx * 8;
    const int tr0 = ty * 4;

    const float* xr0 = x + (size_t)(tok0 + tr0) * DDIM + kb;
    const float* wk  = W + (size_t)kb * NEXP + e0;   // L2-resident

    float accv[4][8];
    #pragma unroll
    for (int t = 0; t < 4; ++t)
        #pragma unroll
        for (int j = 0; j < 8; ++j) accv[t][j] = 0.0f;

    #pragma unroll 2
    for (int k = 0; k < KRANGE; k += 4) {
        float4 xv[4];
        #pragma unroll
        for (int t = 0; t < 4; ++t)
            xv[t] = *(const float4*)(xr0 + (size_t)t * DDIM + k);
        float wv[4][8];
        #pragma unroll
        for (int r = 0; r < 4; ++r) {
            const float* wrow = wk + (size_t)(k + r) * NEXP;
            *(float4*)&wv[r][0] = *(const float4*)wrow;
            *(float4*)&wv[r][4] = *(const float4*)(wrow + 4);
        }
        #pragma unroll
        for (int r = 0; r < 4; ++r) {        // k ascending per acc element
            const float xs0 = ((const float*)&xv[0])[r];
            const float xs1 = ((const float*)&xv[1])[r];
            const float xs2 = ((const float*)&xv[2])[r];
            const float xs3 = ((const float*)&xv[3])[r];
            #pragma unroll
            for (int j = 0; j < 8; ++j) {
                accv[0][j] = fmaf(xs0, wv[r][j], accv[0][j]);
                accv[1][j] = fmaf(xs1, wv[r][j], accv[1][j]);
                accv[2][j] = fmaf(xs2, wv[r][j], accv[2][j]);
                accv[3][j] = fmaf(xs3, wv[r][j], accv[3][j]);
            }
        }
    }

    // store partial logits pws[s][tok][e], coalesced float4
    float* pb = pws + ((size_t)s * NTOK + tok0) * NEXP;
    #pragma unroll
    for (int t = 0; t < 4; ++t) {
        *(float4*)&pb[(size_t)(tr0 + t) * NEXP + e0]     = *(float4*)&accv[t][0];
        *(float4*)&pb[(size_t)(tr0 + t) * NEXP + e0 + 4] = *(float4*)&accv[t][4];
    }
}

#define ETOK 64   // tokens per epilogue block

__global__ __launch_bounds__(256) void epilogue(
    const float* __restrict__ pws, const float* __restrict__ bias,
    float* __restrict__ out, float* __restrict__ acc_g)
{
    __shared__ int   f_loc[NEXP];
    __shared__ float p_loc[NEXP];
    __shared__ float z_loc;

    const int tid = threadIdx.x;
    const int tx  = tid & 15;         // expert group: 4tx..4tx+3
    const int tg  = tid >> 4;         // token slot 0..15
    const int e0  = tx * 4;

    if (tid < NEXP) { f_loc[tid] = 0; p_loc[tid] = 0.0f; }
    if (tid == 0) z_loc = 0.0f;
    __syncthreads();

    float bb[4];
    *(float4*)bb = *(const float4*)&bias[e0];

    float pacc[4] = {0.f, 0.f, 0.f, 0.f};
    float zacc = 0.0f;

    for (int it = 0; it < ETOK / 16; ++it) {
        const int gt = blockIdx.x * ETOK + it * 16 + tg;

        // sum 8 partials in fixed ascending-s order, then + bias
        float l[4];
        {
            const size_t ro = (size_t)gt * NEXP + e0;
            float4 q[KSPLIT];
            #pragma unroll
            for (int sp = 0; sp < KSPLIT; ++sp)
                q[sp] = *(const float4*)&pws[(size_t)sp * NTOK * NEXP + ro];
            float a0 = q[0].x, a1 = q[0].y, a2 = q[0].z, a3 = q[0].w;
            #pragma unroll
            for (int sp = 1; sp < KSPLIT; ++sp) {
                a0 += q[sp].x; a1 += q[sp].y; a2 += q[sp].z; a3 += q[sp].w;
            }
            l[0] = a0 + bb[0]; l[1] = a1 + bb[1];
            l[2] = a2 + bb[2]; l[3] = a3 + bb[3];
        }

        // local top-2 (stable: ascending e, strict >)
        float v1 = l[0], v2 = -INFINITY;
        int   i1 = e0,   i2 = 0x7fffffff;
        #pragma unroll
        for (int j = 1; j < 4; ++j) {
            float v = l[j]; int e = e0 + j;
            if (v > v1)      { v2 = v1; i2 = i1; v1 = v; i1 = e; }
            else if (v > v2) { v2 = v;  i2 = e; }
        }
        // merge across the 16 lanes of this token (value desc, idx asc)
        #pragma unroll
        for (int off = 1; off < 16; off <<= 1) {
            float o1 = __shfl_xor(v1, off, 16); int oi1 = __shfl_xor(i1, off, 16);
            float o2 = __shfl_xor(v2, off, 16); int oi2 = __shfl_xor(i2, off, 16);
            if (o1 > v1 || (o1 == v1 && oi1 < i1)) {
                float cs = v1; int ci = i1;
                v1 = o1; i1 = oi1;
                if (cs > o2 || (cs == o2 && ci < oi2)) { v2 = cs; i2 = ci;  }
                else                                   { v2 = o2; i2 = oi2; }
            } else {
                if (o1 > v2 || (o1 == v2 && oi1 < i2)) { v2 = o1; i2 = oi1; }
            }
        }
        const float mx = v1;

        float sden[4], dsum = 0.0f;
        #pragma unroll
        for (int j = 0; j < 4; ++j) { sden[j] = __expf(l[j] - mx); dsum += sden[j]; }
        #pragma unroll
        for (int off = 1; off < 16; off <<= 1) dsum += __shfl_xor(dsum, off, 16);
        const float inv = 1.0f / dsum;

        float zsum = 0.0f;
        #pragma unroll
        for (int j = 0; j < 4; ++j) {
            float pj = sden[j] * inv;
            pacc[j] += pj;
            zsum += __expf(pj);
        }
        #pragma unroll
        for (int off = 1; off < 16; off <<= 1) zsum += __shfl_xor(zsum, off, 16);

        if (tx == 0) {
            const float s2 = __expf(v2 - mx);      // s1 == 1
            const float ci = 1.0f / (1.0f + s2);
            out[2 * gt]     = (float)i1;
            out[2 * gt + 1] = (float)i2;
            out[2 * NTOK + 2 * gt]     = ci;
            out[2 * NTOK + 2 * gt + 1] = s2 * ci;
            atomicAdd(&f_loc[i1], 1);
            float lse = __logf(zsum);
            zacc += lse * lse;
        }
    }

    // z: wave-reduce (only tx==0 lanes carry nonzero), one LDS atomic per wave
    #pragma unroll
    for (int off = 1; off < 64; off <<= 1) zacc += __shfl_xor(zacc, off);
    if ((tid & 63) == 0) atomicAdd(&z_loc, zacc);

    // P: fold token-groups within wave, then LDS
    #pragma unroll
    for (int j = 0; j < 4; ++j) {
        pacc[j] += __shfl_xor(pacc[j], 16);
        pacc[j] += __shfl_xor(pacc[j], 32);
    }
    if ((tid & 63) < 16) {
        #pragma unroll
        for (int j = 0; j < 4; ++j) atomicAdd(&p_loc[e0 + j], pacc[j]);
    }

    __syncthreads();
    if (tid < NEXP) {
        atomicAdd(&acc_g[64 + tid], p_loc[tid]);
        if (f_loc[tid]) atomicAdd(&acc_g[tid], (float)f_loc[tid]);
    }
    if (tid == 0) atomicAdd(&acc_g[128], z_loc);
}

__global__ void gate_finalize(const float* __restrict__ acc, float* __restrict__ out) {
    int e = threadIdx.x;  // 64 threads
    float v = acc[e] * acc[64 + e];
    #pragma unroll
    for (int off = 32; off > 0; off >>= 1) v += __shfl_down(v, off);
    if (e == 0) {
        const float NT = (float)NTOK;
        out[2 * NTOK * 2]     = 0.01f * (v / (float)NEXP) / (NT * NT);
        out[2 * NTOK * 2 + 1] = 0.1f * acc[128] / NT;
    }
}

extern "C" void kernel_launch(void* const* d_in, const int* in_sizes, int n_in,
                              void* d_out, int out_size, void* d_ws, size_t ws_size,
                              hipStream_t stream) {
    const float* x    = (const float*)d_in[0];
    const float* W    = (const float*)d_in[1];
    const float* bias = (const float*)d_in[2];
    float* out = (float*)d_out;
    float* acc = (float*)d_ws;
    float* pws = acc + PART_OFF;

    zero_acc<<<1, 256, 0, stream>>>(acc);
    gemm_part<<<KSPLIT * (NTOK / MT), 256, 0, stream>>>(x, W, pws);
    epilogue<<<NTOK / ETOK, 256, 0, stream>>>(pws, bias, out, acc);
    gate_finalize<<<1, 64, 0, stream>>>(acc, out);
}

// Round 11
// 82.545 us; speedup vs baseline: 1.5282x; 1.5282x over previous
//
#include <hip/hip_runtime.h>
#include <math.h>

#define NTOK 16384
#define DDIM 2048
#define NEXP 64
#define MT   64                  // tokens per block (= lanes of a wave)
#define KSPLIT 4
#define KRANGE (DDIM / KSPLIT)   // 512
#define KC   32                  // k per LDS chunk
#define NCH  (KRANGE / KC)       // 16

// ws layout (floats): [0..63] f counts, [64..127] P sums, [128] sum lse^2,
// [256 ...] partial logits: [KSPLIT][NTOK][NEXP]
#define PART_OFF 256

// Flat-GEMM structure: wave = 64 tokens (lane = token) x 8 experts.
// W[k][e0..e0+7] is wave-uniform -> scalar loads (s_load) + v_fmac v,s,v:
// W costs ZERO VALU/LDS/vmcnt resources. x staged in LDS, 1 ds_read_b128
// per 32 FMA-inst -> LDS pipe 49k cyc/CU < 65.5k FMA wall.
//
// x LDS tile [64 tok][32 k]: lane reads its own row (stride 128 B). Granule
// swizzle g = s2 ^ (lane&7): per instruction, each bank serves exactly 8
// accesses (the b128 minimum); linear layout would put all 64 lanes on one
// 4-bank quad (8x slower). Inverse swizzle applied on the gload source.

__device__ __forceinline__ void gload16(const float* g, const float* lds) {
    __builtin_amdgcn_global_load_lds(
        (const __attribute__((address_space(1))) unsigned int*)g,
        (__attribute__((address_space(3))) unsigned int*)lds, 16, 0, 0);
}

__global__ void zero_acc(float* acc) {
    int t = threadIdx.x;
    if (t < 129) acc[t] = 0.0f;
}

__global__ __launch_bounds__(512, 8) void gemm_part(
    const float* __restrict__ x, const float* __restrict__ W,
    float* __restrict__ pws)
{
    __shared__ __align__(16) float xb[2][MT * KC];   // 2 x 8 KB

    const int tid  = threadIdx.x;
    const int tb   = blockIdx.x & (NTOK / MT - 1);  // token block 0..255
    const int s    = blockIdx.x >> 8;               // k-split 0..3
    const int tok0 = tb * MT;
    const int kb   = s * KRANGE;

    const int lane = tid & 63;                       // token within block
    const int e0   = __builtin_amdgcn_readfirstlane(tid >> 6) * 8; // SGPR!

    // --- staging: 1 x 16 B per thread; LDS slot tid*16 B ->
    // row = tid>>3, lds granule = tid&7; global granule = lds ^ (row&7).
    const int srow = tid >> 3;
    const int sg   = (tid & 7) ^ (srow & 7);
    const float* xsrc = x + (size_t)(tok0 + srow) * DDIM + kb + (sg << 2);

    float acc[8];
    #pragma unroll
    for (int j = 0; j < 8; ++j) acc[j] = 0.0f;

    const int l7    = lane & 7;
    const int xbase = lane * KC;                     // lane's row (floats)
    const float* wks = W + (size_t)kb * NEXP + e0;   // uniform scalar base

    gload16(xsrc, &xb[0][tid * 4]);

    #pragma unroll 1
    for (int cc = 0; cc < NCH; cc += 2) {
        #pragma unroll
        for (int h = 0; h < 2; ++h) {
            const int c = cc + h;                    // c&1 == h
            __syncthreads();   // chunk c staged (vmcnt drained); buf h free
            if (c + 1 < NCH)
                gload16(xsrc + (c + 1) * KC, &xb[h ^ 1][tid * 4]);
            const float* xcb = xb[h];
            const float* wkc = wks + (size_t)c * KC * NEXP;
            #pragma unroll
            for (int s2 = 0; s2 < KC / 4; ++s2) {
                float xv[4];
                *(float4*)xv =
                    *(const float4*)&xcb[xbase + ((s2 ^ l7) << 2)];
                #pragma unroll
                for (int r = 0; r < 4; ++r) {        // k ascending
                    const float* wrow = wkc + (size_t)(4 * s2 + r) * NEXP;
                    #pragma unroll
                    for (int j = 0; j < 8; ++j)      // wrow[j]: SGPR operand
                        acc[j] = fmaf(xv[r], wrow[j], acc[j]);
                }
            }
        }
    }

    // store partial logits pws[s][tok][e]
    float* pb = pws + ((size_t)s * NTOK + tok0) * NEXP;
    *(float4*)&pb[(size_t)lane * NEXP + e0]     = *(float4*)&acc[0];
    *(float4*)&pb[(size_t)lane * NEXP + e0 + 4] = *(float4*)&acc[4];
}

#define ETOK 64   // tokens per epilogue block

__global__ __launch_bounds__(256) void epilogue(
    const float* __restrict__ pws, const float* __restrict__ bias,
    float* __restrict__ out, float* __restrict__ acc_g)
{
    __shared__ int   f_loc[NEXP];
    __shared__ float p_loc[NEXP];
    __shared__ float z_loc;

    const int tid = threadIdx.x;
    const int tx  = tid & 15;         // expert group: 4tx..4tx+3
    const int tg  = tid >> 4;         // token slot 0..15
    const int e0  = tx * 4;

    if (tid < NEXP) { f_loc[tid] = 0; p_loc[tid] = 0.0f; }
    if (tid == 0) z_loc = 0.0f;
    __syncthreads();

    float bb[4];
    *(float4*)bb = *(const float4*)&bias[e0];

    float pacc[4] = {0.f, 0.f, 0.f, 0.f};
    float zacc = 0.0f;

    for (int it = 0; it < ETOK / 16; ++it) {
        const int gt = blockIdx.x * ETOK + it * 16 + tg;

        // sum 4 partials in fixed ascending-s order, then + bias
        float l[4];
        {
            const size_t ro = (size_t)gt * NEXP + e0;
            float4 q0 = *(const float4*)&pws[ro];
            float4 q1 = *(const float4*)&pws[(size_t)1 * NTOK * NEXP + ro];
            float4 q2 = *(const float4*)&pws[(size_t)2 * NTOK * NEXP + ro];
            float4 q3 = *(const float4*)&pws[(size_t)3 * NTOK * NEXP + ro];
            l[0] = ((q0.x + q1.x) + q2.x) + q3.x + bb[0];
            l[1] = ((q0.y + q1.y) + q2.y) + q3.y + bb[1];
            l[2] = ((q0.z + q1.z) + q2.z) + q3.z + bb[2];
            l[3] = ((q0.w + q1.w) + q2.w) + q3.w + bb[3];
        }

        // local top-2 (stable: ascending e, strict >)
        float v1 = l[0], v2 = -INFINITY;
        int   i1 = e0,   i2 = 0x7fffffff;
        #pragma unroll
        for (int j = 1; j < 4; ++j) {
            float v = l[j]; int e = e0 + j;
            if (v > v1)      { v2 = v1; i2 = i1; v1 = v; i1 = e; }
            else if (v > v2) { v2 = v;  i2 = e; }
        }
        // merge across the 16 lanes of this token (value desc, idx asc)
        #pragma unroll
        for (int off = 1; off < 16; off <<= 1) {
            float o1 = __shfl_xor(v1, off, 16); int oi1 = __shfl_xor(i1, off, 16);
            float o2 = __shfl_xor(v2, off, 16); int oi2 = __shfl_xor(i2, off, 16);
            if (o1 > v1 || (o1 == v1 && oi1 < i1)) {
                float cs = v1; int ci = i1;
                v1 = o1; i1 = oi1;
                if (cs > o2 || (cs == o2 && ci < oi2)) { v2 = cs; i2 = ci;  }
                else                                   { v2 = o2; i2 = oi2; }
            } else {
                if (o1 > v2 || (o1 == v2 && oi1 < i2)) { v2 = o1; i2 = oi1; }
            }
        }
        const float mx = v1;

        float sden[4], dsum = 0.0f;
        #pragma unroll
        for (int j = 0; j < 4; ++j) { sden[j] = __expf(l[j] - mx); dsum += sden[j]; }
        #pragma unroll
        for (int off = 1; off < 16; off <<= 1) dsum += __shfl_xor(dsum, off, 16);
        const float inv = 1.0f / dsum;

        float zsum = 0.0f;
        #pragma unroll
        for (int j = 0; j < 4; ++j) {
            float pj = sden[j] * inv;
            pacc[j] += pj;
            zsum += __expf(pj);
        }
        #pragma unroll
        for (int off = 1; off < 16; off <<= 1) zsum += __shfl_xor(zsum, off, 16);

        if (tx == 0) {
            const float s2 = __expf(v2 - mx);      // s1 == 1
            const float ci = 1.0f / (1.0f + s2);
            out[2 * gt]     = (float)i1;
            out[2 * gt + 1] = (float)i2;
            out[2 * NTOK + 2 * gt]     = ci;
            out[2 * NTOK + 2 * gt + 1] = s2 * ci;
            atomicAdd(&f_loc[i1], 1);
            float lse = __logf(zsum);
            zacc += lse * lse;
        }
    }

    // z: wave-reduce (only tx==0 lanes carry nonzero), one LDS atomic per wave
    #pragma unroll
    for (int off = 1; off < 64; off <<= 1) zacc += __shfl_xor(zacc, off);
    if ((tid & 63) == 0) atomicAdd(&z_loc, zacc);

    // P: fold token-groups within wave, then LDS
    #pragma unroll
    for (int j = 0; j < 4; ++j) {
        pacc[j] += __shfl_xor(pacc[j], 16);
        pacc[j] += __shfl_xor(pacc[j], 32);
    }
    if ((tid & 63) < 16) {
        #pragma unroll
        for (int j = 0; j < 4; ++j) atomicAdd(&p_loc[e0 + j], pacc[j]);
    }

    __syncthreads();
    if (tid < NEXP) {
        atomicAdd(&acc_g[64 + tid], p_loc[tid]);
        if (f_loc[tid]) atomicAdd(&acc_g[tid], (float)f_loc[tid]);
    }
    if (tid == 0) atomicAdd(&acc_g[128], z_loc);
}

__global__ void gate_finalize(const float* __restrict__ acc, float* __restrict__ out) {
    int e = threadIdx.x;  // 64 threads
    float v = acc[e] * acc[64 + e];
    #pragma unroll
    for (int off = 32; off > 0; off >>= 1) v += __shfl_down(v, off);
    if (e == 0) {
        const float NT = (float)NTOK;
        out[2 * NTOK * 2]     = 0.01f * (v / (float)NEXP) / (NT * NT);
        out[2 * NTOK * 2 + 1] = 0.1f * acc[128] / NT;
    }
}

extern "C" void kernel_launch(void* const* d_in, const int* in_sizes, int n_in,
                              void* d_out, int out_size, void* d_ws, size_t ws_size,
                              hipStream_t stream) {
    const float* x    = (const float*)d_in[0];
    const float* W    = (const float*)d_in[1];
    const float* bias = (const float*)d_in[2];
    float* out = (float*)d_out;
    float* acc = (float*)d_ws;
    float* pws = acc + PART_OFF;

    zero_acc<<<1, 256, 0, stream>>>(acc);
    gemm_part<<<KSPLIT * (NTOK / MT), 512, 0, stream>>>(x, W, pws);
    epilogue<<<NTOK / ETOK, 256, 0, stream>>>(pws, bias, out, acc);
    gate_finalize<<<1, 64, 0, stream>>>(acc, out);
}